// Round 5
// baseline (1998.620 us; speedup 1.0000x reference)
//
#include <hip/hip_runtime.h>

#define DD 8
#define SS 64
#define HH 128
#define OUTD 8
#define TT 2049
#define BB 32
#define WINW 16
#define NWIN 128
#define PP 28

typedef __attribute__((ext_vector_type(8))) short short8v;
typedef __attribute__((ext_vector_type(4))) float f32x4;

__device__ __forceinline__ float softplus_f(float x){
    return fmaxf(x, 0.f) + log1pf(__expf(-fabsf(x)));
}
__device__ __forceinline__ float sigmoid_f(float x){
    return 1.f / (1.f + __expf(-x));
}
__device__ __forceinline__ float tanh_f(float x){
    float e = __expf(2.f * x);
    return 1.f - 2.f / (e + 1.f);
}
__device__ __forceinline__ unsigned short f2bf(float f){
    unsigned u = __builtin_bit_cast(unsigned, f);
    unsigned r = (u + 0x7FFFu + ((u >> 16) & 1u)) >> 16;
    return (unsigned short)r;
}
__device__ __forceinline__ unsigned pk2(float a, float b){
    return (unsigned)f2bf(a) | ((unsigned)f2bf(b) << 16);
}

// ---------------- signatures: s1 (B,NWIN,D), s2 (B,NWIN,P) ----------------
__global__ void sig_kernel(const float* __restrict__ x,
                           float* __restrict__ s1o, float* __restrict__ s2o){
    int w = blockIdx.x * blockDim.x + threadIdx.x;
    if (w >= BB * NWIN) return;
    int b = w >> 7, n = w & (NWIN - 1);
    const float* xp = x + ((size_t)b * TT + (size_t)n * WINW) * DD;
    float prev[DD], cum[DD], s1v[DD], M[DD][DD];
    #pragma unroll
    for (int i = 0; i < DD; ++i){
        cum[i] = 0.f; s1v[i] = 0.f;
        #pragma unroll
        for (int j = 0; j < DD; ++j) M[i][j] = 0.f;
    }
    #pragma unroll
    for (int i = 0; i < DD; ++i) prev[i] = xp[i];
    for (int t = 0; t < WINW; ++t){
        float cur[DD], del[DD];
        #pragma unroll
        for (int i = 0; i < DD; ++i) cur[i] = xp[(t + 1) * DD + i];
        #pragma unroll
        for (int i = 0; i < DD; ++i) del[i] = cur[i] - prev[i];
        #pragma unroll
        for (int i = 0; i < DD; ++i){
            #pragma unroll
            for (int j = 0; j < DD; ++j) M[i][j] += cum[i] * del[j];
        }
        #pragma unroll
        for (int i = 0; i < DD; ++i){ cum[i] += del[i]; s1v[i] += del[i]; prev[i] = cur[i]; }
    }
    #pragma unroll
    for (int i = 0; i < DD; ++i) s1o[(size_t)w * DD + i] = s1v[i];
    int p = 0;
    #pragma unroll
    for (int i = 0; i < DD; ++i){
        #pragma unroll
        for (int j = i + 1; j < DD; ++j){ s2o[(size_t)w * PP + p] = 0.5f * (M[i][j] - M[j][i]); ++p; }
    }
}

// image position helper (in shorts): k-row k, col nn of a [K/32][64][8] B-image
#define BPOS(k, nn) ((((k) >> 5) * 64 + (((k) >> 3) & 3) * 16 + (nn)) * 8 + ((k) & 7))

// ---------------- main scan: 2 chains per block, 16 waves, MFMA ----------------
__global__ __launch_bounds__(1024, 1) void scan_kernel(
    const float* __restrict__ x,
    const float* __restrict__ Wi0, const float* __restrict__ bi0,
    const float* __restrict__ Wi1, const float* __restrict__ bi1,
    const float* __restrict__ Wi2, const float* __restrict__ bi2,
    const float* __restrict__ Wv0, const float* __restrict__ bv0,
    const float* __restrict__ Wv1, const float* __restrict__ bv1,
    const float* __restrict__ Wv2, const float* __restrict__ bv2,
    const float* __restrict__ Wr,  const float* __restrict__ br,
    const float* __restrict__ s1g, const float* __restrict__ s2g,
    float* __restrict__ out)
{
    const int tid = threadIdx.x;
    const int w   = tid >> 6;   // wave 0..15
    const int l   = tid & 63;   // lane
    const int lg  = l >> 4;     // lane group 0..3
    const int ln  = l & 15;     // n-col within MFMA tile
    const int b0  = blockIdx.x * 2;

    // A-fragment images (bf16) for W0 (8 m-tiles x 2 ks) and W1 (8 x 4)
    __shared__ __align__(16) short A0img[8 * 2 * 64 * 8];   // 16 KB
    __shared__ __align__(16) short A1img[8 * 4 * 64 * 8];   // 32 KB
    // B-fragment images
    __shared__ __align__(16) short BpH[2 * 64 * 8];         // h   (K=64,  N=2)
    __shared__ __align__(16) short Bp0[4 * 64 * 8];         // z0  (K=128, N=2)
    __shared__ __align__(16) short Bp1[4 * 64 * 8];         // z1  (K=128, N=2)
    __shared__ __align__(16) short Bp7[2 * 64 * 8];         // u   (K=64,  N=16)
    __shared__ __align__(16) short Bp8[4 * 64 * 8];         // t0  (K=128, N=16)
    __shared__ __align__(16) short Bp9[4 * 64 * 8];         // q   (K=128, N=16)
    __shared__ __align__(16) float s0p[2 * HH], s1p[2 * HH];
    __shared__ __align__(16) float Vl[2 * 512], Rf[2 * 512];
    __shared__ __align__(16) float hf[2 * SS];
    __shared__ __align__(16) float bv0L[HH], bv1L[HH], bv2L[512];
    __shared__ __align__(16) float WrL[OUTD * SS];
    __shared__ float brL[OUTD];
    __shared__ __align__(16) float sAll[2 * NWIN * DD];     // 8 KB
    __shared__ __align__(16) float bAll[2 * NWIN * PP];     // 28 KB
    __shared__ __align__(16) float outL[2 * (NWIN + 1) * OUTD]; // 8.25 KB

    // -------- prologue: pack weight images, load W2 reg-frags, stage signatures --------
    for (int i = tid; i < 8 * 2 * 64 * 8; i += 1024){
        int m = i >> 10, ks = (i >> 9) & 1, ll = (i >> 3) & 63, j = i & 7;
        A0img[i] = (short)f2bf(Wv0[(m * 16 + (ll & 15)) * SS + ks * 32 + (ll >> 4) * 8 + j]);
    }
    for (int i = tid; i < 8 * 4 * 64 * 8; i += 1024){
        int m = i >> 11, ks = (i >> 9) & 3, ll = (i >> 3) & 63, j = i & 7;
        A1img[i] = (short)f2bf(Wv1[(m * 16 + (ll & 15)) * HH + ks * 32 + (ll >> 4) * 8 + j]);
    }
    short8v A2f[2][4];   // W2 rows 32w .. 32w+31
    #pragma unroll
    for (int t = 0; t < 2; ++t)
        #pragma unroll
        for (int ks = 0; ks < 4; ++ks){
            const float* p = Wv2 + (size_t)(32 * w + t * 16 + ln) * HH + ks * 32 + lg * 8;
            short8v f;
            #pragma unroll
            for (int j = 0; j < 8; ++j) f[j] = (short)f2bf(p[j]);
            A2f[t][ks] = f;
        }
    if (tid < HH){ bv0L[tid] = bv0[tid]; bv1L[tid] = bv1[tid]; }
    if (tid < 512){ bv2L[tid] = bv2[tid]; WrL[tid] = Wr[tid]; }
    if (tid < OUTD) brL[tid] = br[tid];
    for (int i = tid; i < 2 * NWIN * DD; i += 1024){
        int c = i >> 10;
        sAll[i] = s1g[(size_t)(b0 + c) * NWIN * DD + (i & 1023)];
    }
    for (int i = tid; i < 2 * NWIN * PP; i += 1024){
        int c = i / (NWIN * PP);
        bAll[i] = s2g[(size_t)(b0 + c) * NWIN * PP + (i - c * NWIN * PP)];
    }
    __syncthreads();

    // -------- initial MLP (f32, once); reuse s0p/s1p as scratch --------
    if (tid < 256){
        int c = tid >> 7, r = tid & 127;
        float acc = bi0[r];
        const float* x0 = x + (size_t)(b0 + c) * TT * DD;
        #pragma unroll
        for (int k = 0; k < DD; ++k) acc += Wi0[r * DD + k] * x0[k];
        s0p[c * HH + r] = softplus_f(acc);
    }
    __syncthreads();
    if (tid < 256){
        int c = tid >> 7, r = tid & 127;
        float acc = bi1[r];
        const f32x4* wv = (const f32x4*)(Wi1 + (size_t)r * HH);
        const f32x4* zv = (const f32x4*)&s0p[c * HH];
        #pragma unroll 8
        for (int k = 0; k < 32; ++k){
            f32x4 a = wv[k], z = zv[k];
            acc += a.x * z.x + a.y * z.y + a.z * z.z + a.w * z.w;
        }
        s1p[c * HH + r] = softplus_f(acc);
    }
    __syncthreads();
    if (tid < 128){
        int c = tid >> 6, s = tid & 63;
        float acc = bi2[s];
        const f32x4* wv = (const f32x4*)(Wi2 + (size_t)s * HH);
        const f32x4* zv = (const f32x4*)&s1p[c * HH];
        #pragma unroll 8
        for (int k = 0; k < 32; ++k){
            f32x4 a = wv[k], z = zv[k];
            acc += a.x * z.x + a.y * z.y + a.z * z.z + a.w * z.w;
        }
        hf[c * SS + s] = acc;
        BpH[BPOS(s, c)] = (short)f2bf(acc);
    }
    __syncthreads();

    const f32x4 zero4 = {0.f, 0.f, 0.f, 0.f};

    // -------- scan --------
    for (int n = 0; n < NWIN; ++n){
        // ---- stage A: S1 (waves 0-7) || readout h_n (waves 8-9) ----
        if (w < 8){
            f32x4 acc = zero4;
            #pragma unroll
            for (int ks = 0; ks < 2; ++ks)
                acc = __builtin_amdgcn_mfma_f32_16x16x32_bf16(
                    *(const short8v*)&A0img[((w * 2 + ks) * 64 + l) * 8],
                    *(const short8v*)&BpH[(ks * 64 + l) * 8], acc, 0, 0, 0);
            if (ln < 2){
                int c = ln, rb = w * 16 + lg * 4;
                f32x4 bv = *(const f32x4*)&bv0L[rb];
                f32x4 sg; float z[4];
                #pragma unroll
                for (int r = 0; r < 4; ++r){
                    float p = acc[r] + bv[r];
                    z[r] = softplus_f(p); sg[r] = sigmoid_f(p);
                }
                *(f32x4*)&s0p[c * HH + rb] = sg;
                uint2 pk; pk.x = pk2(z[0], z[1]); pk.y = pk2(z[2], z[3]);
                *(uint2*)&Bp0[BPOS(rb, c)] = pk;
            }
        } else if (w < 10){
            int c = w - 8, o = l >> 3, q = l & 7;
            f32x4 w0 = *(const f32x4*)&WrL[o * SS + q * 8];
            f32x4 w1 = *(const f32x4*)&WrL[o * SS + q * 8 + 4];
            f32x4 h0 = *(const f32x4*)&hf[c * SS + q * 8];
            f32x4 h1 = *(const f32x4*)&hf[c * SS + q * 8 + 4];
            float acc = w0.x*h0.x + w0.y*h0.y + w0.z*h0.z + w0.w*h0.w
                      + w1.x*h1.x + w1.y*h1.y + w1.z*h1.z + w1.w*h1.w;
            acc += __shfl_xor(acc, 1); acc += __shfl_xor(acc, 2); acc += __shfl_xor(acc, 4);
            if (q == 0) outL[c * (NWIN + 1) * OUTD + n * OUTD + o] = brL[o] + acc;
        }
        __syncthreads();

        // ---- S3: z1 = sp(W1 @ z0) (waves 0-7) ----
        if (w < 8){
            f32x4 acc = zero4;
            #pragma unroll
            for (int ks = 0; ks < 4; ++ks)
                acc = __builtin_amdgcn_mfma_f32_16x16x32_bf16(
                    *(const short8v*)&A1img[((w * 4 + ks) * 64 + l) * 8],
                    *(const short8v*)&Bp0[(ks * 64 + l) * 8], acc, 0, 0, 0);
            if (ln < 2){
                int c = ln, rb = w * 16 + lg * 4;
                f32x4 bv = *(const f32x4*)&bv1L[rb];
                f32x4 sg; float z[4];
                #pragma unroll
                for (int r = 0; r < 4; ++r){
                    float p = acc[r] + bv[r];
                    z[r] = softplus_f(p); sg[r] = sigmoid_f(p);
                }
                *(f32x4*)&s1p[c * HH + rb] = sg;
                uint2 pk; pk.x = pk2(z[0], z[1]); pk.y = pk2(z[2], z[3]);
                *(uint2*)&Bp1[BPOS(rb, c)] = pk;
            }
        }
        __syncthreads();

        // ---- S4: V = tanh(W2 @ z1 + bv2) (all 16 waves, rows 32w..32w+31) ----
        {
            f32x4 acc0 = zero4, acc1 = zero4;
            #pragma unroll
            for (int ks = 0; ks < 4; ++ks){
                short8v bfr = *(const short8v*)&Bp1[(ks * 64 + l) * 8];
                acc0 = __builtin_amdgcn_mfma_f32_16x16x32_bf16(A2f[0][ks], bfr, acc0, 0, 0, 0);
                acc1 = __builtin_amdgcn_mfma_f32_16x16x32_bf16(A2f[1][ks], bfr, acc1, 0, 0, 0);
            }
            if (ln < 2){
                int c = ln;
                #pragma unroll
                for (int t = 0; t < 2; ++t){
                    int rb = 32 * w + t * 16 + lg * 4;
                    f32x4 av = t ? acc1 : acc0;
                    f32x4 bv = *(const f32x4*)&bv2L[rb];
                    f32x4 vv;
                    #pragma unroll
                    for (int r = 0; r < 4; ++r) vv[r] = tanh_f(av[r] + bv[r]);
                    *(f32x4*)&Vl[c * 512 + rb] = vv;
                }
            }
        }
        __syncthreads();

        // ---- u[d] = sum_e C[d][e] V[e]  (256 threads; 4 cols each -> Bp7) ----
        if (tid < 256){
            int c = tid >> 7, d = (tid >> 4) & 7, cg = tid & 15;
            const float* bco = &bAll[c * (NWIN * PP) + n * PP];
            f32x4 acc = zero4;
            #pragma unroll
            for (int e = 0; e < DD; ++e){
                if (e == d) continue;
                float coef = (e < d) ?  bco[((e * (15 - e)) >> 1) + d - e - 1]
                                     : -bco[((d * (15 - d)) >> 1) + e - d - 1];
                f32x4 v4 = *(const f32x4*)&Vl[c * 512 + e * 64 + cg * 4];
                acc.x += coef * v4.x; acc.y += coef * v4.y;
                acc.z += coef * v4.z; acc.w += coef * v4.w;
            }
            int k0 = cg * 4, nn = c * 8 + d;
            uint2 pk; pk.x = pk2(acc.x, acc.y); pk.y = pk2(acc.z, acc.w);
            *(uint2*)&Bp7[BPOS(k0, nn)] = pk;
        }
        __syncthreads();

        // ---- S7: t0 = s0' * (W0 @ u) (waves 8-15, all 16 cols) ----
        if (w >= 8){
            int mt = w - 8;
            f32x4 acc = zero4;
            #pragma unroll
            for (int ks = 0; ks < 2; ++ks)
                acc = __builtin_amdgcn_mfma_f32_16x16x32_bf16(
                    *(const short8v*)&A0img[((mt * 2 + ks) * 64 + l) * 8],
                    *(const short8v*)&Bp7[(ks * 64 + l) * 8], acc, 0, 0, 0);
            int c = ln >> 3, rb = mt * 16 + lg * 4;
            f32x4 sg = *(const f32x4*)&s0p[c * HH + rb];
            uint2 pk; pk.x = pk2(sg[0] * acc[0], sg[1] * acc[1]);
            pk.y = pk2(sg[2] * acc[2], sg[3] * acc[3]);
            *(uint2*)&Bp8[BPOS(rb, ln)] = pk;
        }
        __syncthreads();

        // ---- S8: q = s1' * (W1 @ t0) (waves 0-7) ----
        if (w < 8){
            f32x4 acc = zero4;
            #pragma unroll
            for (int ks = 0; ks < 4; ++ks)
                acc = __builtin_amdgcn_mfma_f32_16x16x32_bf16(
                    *(const short8v*)&A1img[((w * 4 + ks) * 64 + l) * 8],
                    *(const short8v*)&Bp8[(ks * 64 + l) * 8], acc, 0, 0, 0);
            int c = ln >> 3, rb = w * 16 + lg * 4;
            f32x4 sg = *(const f32x4*)&s1p[c * HH + rb];
            uint2 pk; pk.x = pk2(sg[0] * acc[0], sg[1] * acc[1]);
            pk.y = pk2(sg[2] * acc[2], sg[3] * acc[3]);
            *(uint2*)&Bp9[BPOS(rb, ln)] = pk;
        }
        __syncthreads();

        // ---- S9: R = (1-V^2) * (W2 @ q), diagonal col d=w>>1 (all waves) ----
        {
            f32x4 acc0 = zero4, acc1 = zero4;
            #pragma unroll
            for (int ks = 0; ks < 4; ++ks){
                short8v bfr = *(const short8v*)&Bp9[(ks * 64 + l) * 8];
                acc0 = __builtin_amdgcn_mfma_f32_16x16x32_bf16(A2f[0][ks], bfr, acc0, 0, 0, 0);
                acc1 = __builtin_amdgcn_mfma_f32_16x16x32_bf16(A2f[1][ks], bfr, acc1, 0, 0, 0);
            }
            int dtar = w >> 1;
            if ((ln & 7) == dtar){
                int c = ln >> 3;
                #pragma unroll
                for (int t = 0; t < 2; ++t){
                    int rb = 32 * w + t * 16 + lg * 4;
                    f32x4 av = t ? acc1 : acc0;
                    f32x4 vv = *(const f32x4*)&Vl[c * 512 + rb];
                    f32x4 rr;
                    #pragma unroll
                    for (int r = 0; r < 4; ++r) rr[r] = (1.f - vv[r] * vv[r]) * av[r];
                    *(f32x4*)&Rf[c * 512 + rb] = rr;
                }
            }
        }
        __syncthreads();

        // ---- h update ----
        if (tid < 128){
            int c = tid >> 6, s = tid & 63;
            const float* aL = &sAll[c * (NWIN * DD) + n * DD];
            float av = 0.f, y = 0.f;
            #pragma unroll
            for (int d = 0; d < DD; ++d){
                av += aL[d] * Vl[c * 512 + d * 64 + s];
                y  += Rf[c * 512 + d * 64 + s];
            }
            float hn = hf[c * SS + s] + av + y;
            hf[c * SS + s] = hn;
            BpH[BPOS(s, c)] = (short)f2bf(hn);
        }
        __syncthreads();
    }

    // final readout h_NWIN
    if (w == 8 || w == 9){
        int c = w - 8, o = l >> 3, q = l & 7;
        f32x4 w0 = *(const f32x4*)&WrL[o * SS + q * 8];
        f32x4 w1 = *(const f32x4*)&WrL[o * SS + q * 8 + 4];
        f32x4 h0 = *(const f32x4*)&hf[c * SS + q * 8];
        f32x4 h1 = *(const f32x4*)&hf[c * SS + q * 8 + 4];
        float acc = w0.x*h0.x + w0.y*h0.y + w0.z*h0.z + w0.w*h0.w
                  + w1.x*h1.x + w1.y*h1.y + w1.z*h1.z + w1.w*h1.w;
        acc += __shfl_xor(acc, 1); acc += __shfl_xor(acc, 2); acc += __shfl_xor(acc, 4);
        if (q == 0) outL[c * (NWIN + 1) * OUTD + NWIN * OUTD + o] = brL[o] + acc;
    }
    __syncthreads();

    // flush outputs
    for (int i = tid; i < 2 * (NWIN + 1) * OUTD; i += 1024){
        int c = (i >= (NWIN + 1) * OUTD) ? 1 : 0;
        int rem = i - c * (NWIN + 1) * OUTD;
        out[(size_t)(b0 + c) * (NWIN + 1) * OUTD + rem] = outL[i];
    }
}

extern "C" void kernel_launch(void* const* d_in, const int* in_sizes, int n_in,
                              void* d_out, int out_size, void* d_ws, size_t ws_size,
                              hipStream_t stream){
    const float* x   = (const float*)d_in[1];
    const float* Wi0 = (const float*)d_in[2];
    const float* bi0 = (const float*)d_in[3];
    const float* Wi1 = (const float*)d_in[4];
    const float* bi1 = (const float*)d_in[5];
    const float* Wi2 = (const float*)d_in[6];
    const float* bi2 = (const float*)d_in[7];
    const float* Wv0 = (const float*)d_in[8];
    const float* bv0 = (const float*)d_in[9];
    const float* Wv1 = (const float*)d_in[10];
    const float* bv1 = (const float*)d_in[11];
    const float* Wv2 = (const float*)d_in[12];
    const float* bv2 = (const float*)d_in[13];
    const float* Wr  = (const float*)d_in[14];
    const float* br  = (const float*)d_in[15];
    float* out = (float*)d_out;

    float* s1w = (float*)d_ws;
    float* s2w = s1w + (size_t)BB * NWIN * DD;

    sig_kernel<<<(BB * NWIN + 255) / 256, 256, 0, stream>>>(x, s1w, s2w);
    scan_kernel<<<BB / 2, 1024, 0, stream>>>(x, Wi0, bi0, Wi1, bi1, Wi2, bi2,
                                             Wv0, bv0, Wv1, bv1, Wv2, bv2,
                                             Wr, br, s1w, s2w, out);
}

// Round 6
// 1257.215 us; speedup vs baseline: 1.5897x; 1.5897x over previous
//
#include <hip/hip_runtime.h>

#define DD 8
#define SS 64
#define HH 128
#define OUTD 8
#define TT 2049
#define BB 32
#define WINW 16
#define NWIN 128
#define PP 28

typedef __attribute__((ext_vector_type(8))) short short8v;
typedef __attribute__((ext_vector_type(4))) float f32x4;

__device__ __forceinline__ float softplus_f(float x){
    // max(x,0) + log(1+exp(-|x|)) with HW exp/log; |err| ~1e-7, fine vs bf16 tol
    return fmaxf(x, 0.f) + __logf(1.f + __expf(-fabsf(x)));
}
__device__ __forceinline__ float sigmoid_f(float x){
    return 1.f / (1.f + __expf(-x));
}
__device__ __forceinline__ float tanh_f(float x){
    float e = __expf(2.f * x);
    return 1.f - 2.f / (e + 1.f);
}
__device__ __forceinline__ unsigned short f2bf(float f){
    unsigned u = __builtin_bit_cast(unsigned, f);
    unsigned r = (u + 0x7FFFu + ((u >> 16) & 1u)) >> 16;
    return (unsigned short)r;
}
__device__ __forceinline__ unsigned pk2(float a, float b){
    return (unsigned)f2bf(a) | ((unsigned)f2bf(b) << 16);
}

// ---------------- signatures: s1 (B,NWIN,D), s2 (B,NWIN,P) ----------------
__global__ void sig_kernel(const float* __restrict__ x,
                           float* __restrict__ s1o, float* __restrict__ s2o){
    int w = blockIdx.x * blockDim.x + threadIdx.x;
    if (w >= BB * NWIN) return;
    int b = w >> 7, n = w & (NWIN - 1);
    const float* xp = x + ((size_t)b * TT + (size_t)n * WINW) * DD;
    float prev[DD], cum[DD], s1v[DD], M[DD][DD];
    #pragma unroll
    for (int i = 0; i < DD; ++i){
        cum[i] = 0.f; s1v[i] = 0.f;
        #pragma unroll
        for (int j = 0; j < DD; ++j) M[i][j] = 0.f;
    }
    #pragma unroll
    for (int i = 0; i < DD; ++i) prev[i] = xp[i];
    for (int t = 0; t < WINW; ++t){
        float cur[DD], del[DD];
        #pragma unroll
        for (int i = 0; i < DD; ++i) cur[i] = xp[(t + 1) * DD + i];
        #pragma unroll
        for (int i = 0; i < DD; ++i) del[i] = cur[i] - prev[i];
        #pragma unroll
        for (int i = 0; i < DD; ++i){
            #pragma unroll
            for (int j = 0; j < DD; ++j) M[i][j] += cum[i] * del[j];
        }
        #pragma unroll
        for (int i = 0; i < DD; ++i){ cum[i] += del[i]; s1v[i] += del[i]; prev[i] = cur[i]; }
    }
    #pragma unroll
    for (int i = 0; i < DD; ++i) s1o[(size_t)w * DD + i] = s1v[i];
    int p = 0;
    #pragma unroll
    for (int i = 0; i < DD; ++i){
        #pragma unroll
        for (int j = i + 1; j < DD; ++j){ s2o[(size_t)w * PP + p] = 0.5f * (M[i][j] - M[j][i]); ++p; }
    }
}

// image position (shorts): k-row k, col nn of a [K/32][64][8] B-image
#define BPOS(k, nn) ((((k) >> 5) * 64 + (((k) >> 3) & 3) * 16 + (nn)) * 8 + ((k) & 7))

// ---------------- main scan: 1 chain per block, 8 waves, reg-resident weights ----------------
__global__ __launch_bounds__(512, 2) void scan_kernel(
    const float* __restrict__ x,
    const float* __restrict__ Wi0, const float* __restrict__ bi0,
    const float* __restrict__ Wi1, const float* __restrict__ bi1,
    const float* __restrict__ Wi2, const float* __restrict__ bi2,
    const float* __restrict__ Wv0, const float* __restrict__ bv0,
    const float* __restrict__ Wv1, const float* __restrict__ bv1,
    const float* __restrict__ Wv2, const float* __restrict__ bv2,
    const float* __restrict__ Wr,  const float* __restrict__ br,
    const float* __restrict__ s1g, const float* __restrict__ s2g,
    float* __restrict__ out)
{
    const int tid = threadIdx.x;
    const int w   = tid >> 6;   // wave 0..7  (= m-tile for S1/S3/S7/S8, = d-block for S4/S9)
    const int l   = tid & 63;
    const int lg  = l >> 4;
    const int ln  = l & 15;
    const int b   = blockIdx.x;

    __shared__ __align__(16) short BpH[2 * 64 * 8];   // h  (K=64, col0)
    __shared__ __align__(16) short Bp0[4 * 64 * 8];   // z0 (K=128, col0)
    __shared__ __align__(16) short Bp1[4 * 64 * 8];   // z1 (K=128, cols0-3 dup)
    __shared__ __align__(16) short BpV[2 * 64 * 8];   // V  (K=64, cols0-7 = d)
    __shared__ __align__(16) short Bp8[4 * 64 * 8];   // t0 (K=128, cols0-7)
    __shared__ __align__(16) short Bp9[4 * 64 * 8];   // q  (K=128, cols0-7)
    __shared__ __align__(16) float s0p[HH], s1p[HH];
    __shared__ __align__(16) float Vl[512], Rf[512];
    __shared__ __align__(16) float hfb[2][SS];
    __shared__ __align__(16) float Cm[DD][9];
    __shared__ __align__(16) float bv0L[HH], bv1L[HH], bv2L[512];
    __shared__ __align__(16) float WrL[OUTD * SS];
    __shared__ float brL[OUTD];
    __shared__ __align__(16) float sAll[NWIN * DD];       // 4 KB
    __shared__ __align__(16) float bAll[NWIN * PP];       // 14 KB
    __shared__ __align__(16) float outL[(NWIN + 1) * OUTD];

    // -------- prologue --------
    for (int i = tid; i < 2 * 64 * 8; i += 512){ BpH[i] = 0; BpV[i] = 0; }
    for (int i = tid; i < 4 * 64 * 8; i += 512){ Bp0[i] = 0; Bp1[i] = 0; Bp8[i] = 0; Bp9[i] = 0; }

    // register-resident A-fragments (wave-invariant rows)
    short8v a0f[2], a1f[4];
    short8v a2f0[4], a2f1[4], a2f2[4], a2f3[4];
    #pragma unroll
    for (int ks = 0; ks < 2; ++ks){
        const float* p = Wv0 + (size_t)(w * 16 + ln) * SS + ks * 32 + lg * 8;
        short8v f;
        #pragma unroll
        for (int j = 0; j < 8; ++j) f[j] = (short)f2bf(p[j]);
        a0f[ks] = f;
    }
    #pragma unroll
    for (int ks = 0; ks < 4; ++ks){
        const float* p = Wv1 + (size_t)(w * 16 + ln) * HH + ks * 32 + lg * 8;
        short8v f;
        #pragma unroll
        for (int j = 0; j < 8; ++j) f[j] = (short)f2bf(p[j]);
        a1f[ks] = f;
    }
    #pragma unroll
    for (int ks = 0; ks < 4; ++ks){
        const float* p0 = Wv2 + (size_t)(64 * w + 0 * 16 + ln) * HH + ks * 32 + lg * 8;
        const float* p1 = Wv2 + (size_t)(64 * w + 1 * 16 + ln) * HH + ks * 32 + lg * 8;
        const float* p2 = Wv2 + (size_t)(64 * w + 2 * 16 + ln) * HH + ks * 32 + lg * 8;
        const float* p3 = Wv2 + (size_t)(64 * w + 3 * 16 + ln) * HH + ks * 32 + lg * 8;
        short8v f0, f1, f2, f3;
        #pragma unroll
        for (int j = 0; j < 8; ++j){
            f0[j] = (short)f2bf(p0[j]); f1[j] = (short)f2bf(p1[j]);
            f2[j] = (short)f2bf(p2[j]); f3[j] = (short)f2bf(p3[j]);
        }
        a2f0[ks] = f0; a2f1[ks] = f1; a2f2[ks] = f2; a2f3[ks] = f3;
    }
    if (tid < HH){ bv0L[tid] = bv0[tid]; bv1L[tid] = bv1[tid]; }
    bv2L[tid] = bv2[tid];                 // 512
    WrL[tid]  = Wr[tid];                  // 512
    if (tid < OUTD) brL[tid] = br[tid];
    for (int i = tid; i < NWIN * DD; i += 512) sAll[i] = s1g[(size_t)b * NWIN * DD + i];
    for (int i = tid; i < NWIN * PP; i += 512) bAll[i] = s2g[(size_t)b * NWIN * PP + i];
    __syncthreads();

    // Cmat for step 0 (needs bAll staged)
    if (tid < 64){
        int d = tid >> 3, e = tid & 7;
        float c = 0.f;
        if (e < d)      c =  bAll[((e * (15 - e)) >> 1) + d - e - 1];
        else if (e > d) c = -bAll[((d * (15 - d)) >> 1) + e - d - 1];
        Cm[d][e] = c;
    }
    // initial MLP (f32): s0p/s1p as scratch
    if (tid < HH){
        float acc = bi0[tid];
        const float* x0 = x + (size_t)b * TT * DD;
        #pragma unroll
        for (int k = 0; k < DD; ++k) acc += Wi0[tid * DD + k] * x0[k];
        s0p[tid] = softplus_f(acc);
    }
    __syncthreads();
    if (tid < HH){
        float acc = bi1[tid];
        const f32x4* wv = (const f32x4*)(Wi1 + (size_t)tid * HH);
        const f32x4* zv = (const f32x4*)s0p;
        #pragma unroll 8
        for (int k = 0; k < 32; ++k){
            f32x4 a = wv[k], z = zv[k];
            acc += a.x * z.x + a.y * z.y + a.z * z.z + a.w * z.w;
        }
        s1p[tid] = softplus_f(acc);
    }
    __syncthreads();
    if (tid < SS){
        float acc = bi2[tid];
        const f32x4* wv = (const f32x4*)(Wi2 + (size_t)tid * HH);
        const f32x4* zv = (const f32x4*)s1p;
        #pragma unroll 8
        for (int k = 0; k < 32; ++k){
            f32x4 a = wv[k], z = zv[k];
            acc += a.x * z.x + a.y * z.y + a.z * z.z + a.w * z.w;
        }
        hfb[0][tid] = acc;
        BpH[BPOS(tid, 0)] = (short)f2bf(acc);
    }
    __syncthreads();

    const f32x4 zero4 = {0.f, 0.f, 0.f, 0.f};
    const int rb = w * 16 + lg * 4;

    // -------- scan --------
    for (int n = 0; n < NWIN; ++n){
        // ---- S1: z0 = sp(W0 @ h) ----
        {
            f32x4 acc = zero4;
            acc = __builtin_amdgcn_mfma_f32_16x16x32_bf16(a0f[0], *(const short8v*)&BpH[(0 * 64 + l) * 8], acc, 0, 0, 0);
            acc = __builtin_amdgcn_mfma_f32_16x16x32_bf16(a0f[1], *(const short8v*)&BpH[(1 * 64 + l) * 8], acc, 0, 0, 0);
            if (ln == 0){
                f32x4 bv = *(const f32x4*)&bv0L[rb];
                f32x4 sg; float z[4];
                #pragma unroll
                for (int r = 0; r < 4; ++r){
                    float p = acc[r] + bv[r];
                    z[r] = softplus_f(p); sg[r] = sigmoid_f(p);
                }
                *(f32x4*)&s0p[rb] = sg;
                uint2 pk; pk.x = pk2(z[0], z[1]); pk.y = pk2(z[2], z[3]);
                *(uint2*)&Bp0[BPOS(rb, 0)] = pk;
            }
        }
        __syncthreads();

        // ---- S3: z1 = sp(W1 @ z0), write cols 0-3 dup ----
        {
            f32x4 acc = zero4;
            #pragma unroll
            for (int ks = 0; ks < 4; ++ks)
                acc = __builtin_amdgcn_mfma_f32_16x16x32_bf16(a1f[ks], *(const short8v*)&Bp0[(ks * 64 + l) * 8], acc, 0, 0, 0);
            if (ln == 0){
                f32x4 bv = *(const f32x4*)&bv1L[rb];
                f32x4 sg; float z[4];
                #pragma unroll
                for (int r = 0; r < 4; ++r){
                    float p = acc[r] + bv[r];
                    z[r] = softplus_f(p); sg[r] = sigmoid_f(p);
                }
                *(f32x4*)&s1p[rb] = sg;
                uint2 pk; pk.x = pk2(z[0], z[1]); pk.y = pk2(z[2], z[3]);
                #pragma unroll
                for (int c = 0; c < 4; ++c) *(uint2*)&Bp1[BPOS(rb, c)] = pk;
            }
        }
        __syncthreads();

        // ---- S4: V_d = tanh(W2_d @ z1 + bv2), d = w; epilogue spread over lanes 0-3 ----
        {
            short8v bf[4];
            #pragma unroll
            for (int ks = 0; ks < 4; ++ks) bf[ks] = *(const short8v*)&Bp1[(ks * 64 + l) * 8];
            f32x4 acc0 = zero4, acc1 = zero4, acc2 = zero4, acc3 = zero4;
            #pragma unroll
            for (int ks = 0; ks < 4; ++ks){
                acc0 = __builtin_amdgcn_mfma_f32_16x16x32_bf16(a2f0[ks], bf[ks], acc0, 0, 0, 0);
                acc1 = __builtin_amdgcn_mfma_f32_16x16x32_bf16(a2f1[ks], bf[ks], acc1, 0, 0, 0);
                acc2 = __builtin_amdgcn_mfma_f32_16x16x32_bf16(a2f2[ks], bf[ks], acc2, 0, 0, 0);
                acc3 = __builtin_amdgcn_mfma_f32_16x16x32_bf16(a2f3[ks], bf[ks], acc3, 0, 0, 0);
            }
            #pragma unroll
            for (int t = 0; t < 4; ++t){
                if (ln == t){   // cols 0-3 of Bp1 are duplicates -> lane t holds tile t's values
                    f32x4 av = (t == 0) ? acc0 : (t == 1) ? acc1 : (t == 2) ? acc2 : acc3;
                    int r4 = 64 * w + t * 16 + lg * 4;
                    f32x4 bv = *(const f32x4*)&bv2L[r4];
                    f32x4 vv;
                    #pragma unroll
                    for (int r = 0; r < 4; ++r) vv[r] = tanh_f(av[r] + bv[r]);
                    *(f32x4*)&Vl[r4] = vv;
                    int sl = t * 16 + lg * 4;
                    uint2 pk; pk.x = pk2(vv[0], vv[1]); pk.y = pk2(vv[2], vv[3]);
                    *(uint2*)&BpV[BPOS(sl, w)] = pk;
                }
            }
        }
        __syncthreads();

        // ---- S7: Y = W0 @ V^T (N=8), then t0[:,d] = s0' * sum_e Cm[d][e] Y[:,e] ----
        {
            f32x4 acc = zero4;
            acc = __builtin_amdgcn_mfma_f32_16x16x32_bf16(a0f[0], *(const short8v*)&BpV[(0 * 64 + l) * 8], acc, 0, 0, 0);
            acc = __builtin_amdgcn_mfma_f32_16x16x32_bf16(a0f[1], *(const short8v*)&BpV[(1 * 64 + l) * 8], acc, 0, 0, 0);
            const int d = ln & 7;
            float tm0 = 0.f, tm1 = 0.f, tm2 = 0.f, tm3 = 0.f;
            #pragma unroll
            for (int e = 0; e < 8; ++e){
                float ce = Cm[d][e];
                int src = (l & 48) | e;
                tm0 += ce * __shfl(acc[0], src);
                tm1 += ce * __shfl(acc[1], src);
                tm2 += ce * __shfl(acc[2], src);
                tm3 += ce * __shfl(acc[3], src);
            }
            if (ln < 8){
                f32x4 sg = *(const f32x4*)&s0p[rb];
                uint2 pk; pk.x = pk2(sg[0] * tm0, sg[1] * tm1); pk.y = pk2(sg[2] * tm2, sg[3] * tm3);
                *(uint2*)&Bp8[BPOS(rb, ln)] = pk;
            }
        }
        __syncthreads();

        // ---- S8: q = s1' * (W1 @ t0) (N=8) ----
        {
            f32x4 acc = zero4;
            #pragma unroll
            for (int ks = 0; ks < 4; ++ks)
                acc = __builtin_amdgcn_mfma_f32_16x16x32_bf16(a1f[ks], *(const short8v*)&Bp8[(ks * 64 + l) * 8], acc, 0, 0, 0);
            if (ln < 8){
                f32x4 sg = *(const f32x4*)&s1p[rb];
                uint2 pk; pk.x = pk2(sg[0] * acc[0], sg[1] * acc[1]); pk.y = pk2(sg[2] * acc[2], sg[3] * acc[3]);
                *(uint2*)&Bp9[BPOS(rb, ln)] = pk;
            }
        }
        __syncthreads();

        // ---- S9: R_d = (1-V_d^2) * (W2_d @ q[:,d]), d = w -> extract col w ----
        {
            short8v bf[4];
            #pragma unroll
            for (int ks = 0; ks < 4; ++ks) bf[ks] = *(const short8v*)&Bp9[(ks * 64 + l) * 8];
            f32x4 acc0 = zero4, acc1 = zero4, acc2 = zero4, acc3 = zero4;
            #pragma unroll
            for (int ks = 0; ks < 4; ++ks){
                acc0 = __builtin_amdgcn_mfma_f32_16x16x32_bf16(a2f0[ks], bf[ks], acc0, 0, 0, 0);
                acc1 = __builtin_amdgcn_mfma_f32_16x16x32_bf16(a2f1[ks], bf[ks], acc1, 0, 0, 0);
                acc2 = __builtin_amdgcn_mfma_f32_16x16x32_bf16(a2f2[ks], bf[ks], acc2, 0, 0, 0);
                acc3 = __builtin_amdgcn_mfma_f32_16x16x32_bf16(a2f3[ks], bf[ks], acc3, 0, 0, 0);
            }
            if (ln == w){
                #pragma unroll
                for (int t = 0; t < 4; ++t){
                    f32x4 av = (t == 0) ? acc0 : (t == 1) ? acc1 : (t == 2) ? acc2 : acc3;
                    int r4 = 64 * w + t * 16 + lg * 4;
                    f32x4 vv = *(const f32x4*)&Vl[r4];
                    f32x4 rr;
                    #pragma unroll
                    for (int r = 0; r < 4; ++r) rr[r] = (1.f - vv[r] * vv[r]) * av[r];
                    *(f32x4*)&Rf[r4] = rr;
                }
            }
        }
        __syncthreads();

        // ---- update (wave0) || readout h_n (wave1) || Cmat(n+1) (wave2) ----
        {
            const int cur = n & 1;
            if (w == 0){
                int s = l;
                float hN = hfb[cur][s];
                #pragma unroll
                for (int d = 0; d < DD; ++d)
                    hN += sAll[n * DD + d] * Vl[d * 64 + s] + Rf[d * 64 + s];
                hfb[cur ^ 1][s] = hN;
                BpH[BPOS(s, 0)] = (short)f2bf(hN);
            } else if (w == 1){
                int o = l >> 3, qq = l & 7;
                f32x4 w0 = *(const f32x4*)&WrL[o * SS + qq * 8];
                f32x4 w1 = *(const f32x4*)&WrL[o * SS + qq * 8 + 4];
                f32x4 h0 = *(const f32x4*)&hfb[cur][qq * 8];
                f32x4 h1 = *(const f32x4*)&hfb[cur][qq * 8 + 4];
                float acc = w0.x*h0.x + w0.y*h0.y + w0.z*h0.z + w0.w*h0.w
                          + w1.x*h1.x + w1.y*h1.y + w1.z*h1.z + w1.w*h1.w;
                acc += __shfl_xor(acc, 1); acc += __shfl_xor(acc, 2); acc += __shfl_xor(acc, 4);
                if (qq == 0) outL[n * OUTD + o] = brL[o] + acc;
            } else if (w == 2){
                if (n + 1 < NWIN){
                    int d = l >> 3, e = l & 7;
                    const float* bco = &bAll[(n + 1) * PP];
                    float c = 0.f;
                    if (e < d)      c =  bco[((e * (15 - e)) >> 1) + d - e - 1];
                    else if (e > d) c = -bco[((d * (15 - d)) >> 1) + e - d - 1];
                    Cm[d][e] = c;
                }
            }
        }
        __syncthreads();
    }

    // final readout: h_NWIN is in hfb[0] (NWIN even)
    if (w == 1){
        int o = l >> 3, qq = l & 7;
        f32x4 w0 = *(const f32x4*)&WrL[o * SS + qq * 8];
        f32x4 w1 = *(const f32x4*)&WrL[o * SS + qq * 8 + 4];
        f32x4 h0 = *(const f32x4*)&hfb[0][qq * 8];
        f32x4 h1 = *(const f32x4*)&hfb[0][qq * 8 + 4];
        float acc = w0.x*h0.x + w0.y*h0.y + w0.z*h0.z + w0.w*h0.w
                  + w1.x*h1.x + w1.y*h1.y + w1.z*h1.z + w1.w*h1.w;
        acc += __shfl_xor(acc, 1); acc += __shfl_xor(acc, 2); acc += __shfl_xor(acc, 4);
        if (qq == 0) outL[NWIN * OUTD + o] = brL[o] + acc;
    }
    __syncthreads();

    for (int i = tid; i < (NWIN + 1) * OUTD; i += 512)
        out[(size_t)b * (NWIN + 1) * OUTD + i] = outL[i];
}

extern "C" void kernel_launch(void* const* d_in, const int* in_sizes, int n_in,
                              void* d_out, int out_size, void* d_ws, size_t ws_size,
                              hipStream_t stream){
    const float* x   = (const float*)d_in[1];
    const float* Wi0 = (const float*)d_in[2];
    const float* bi0 = (const float*)d_in[3];
    const float* Wi1 = (const float*)d_in[4];
    const float* bi1 = (const float*)d_in[5];
    const float* Wi2 = (const float*)d_in[6];
    const float* bi2 = (const float*)d_in[7];
    const float* Wv0 = (const float*)d_in[8];
    const float* bv0 = (const float*)d_in[9];
    const float* Wv1 = (const float*)d_in[10];
    const float* bv1 = (const float*)d_in[11];
    const float* Wv2 = (const float*)d_in[12];
    const float* bv2 = (const float*)d_in[13];
    const float* Wr  = (const float*)d_in[14];
    const float* br  = (const float*)d_in[15];
    float* out = (float*)d_out;

    float* s1w = (float*)d_ws;
    float* s2w = s1w + (size_t)BB * NWIN * DD;

    sig_kernel<<<(BB * NWIN + 255) / 256, 256, 0, stream>>>(x, s1w, s2w);
    scan_kernel<<<BB, 512, 0, stream>>>(x, Wi0, bi0, Wi1, bi1, Wi2, bi2,
                                        Wv0, bv0, Wv1, bv1, Wv2, bv2,
                                        Wr, br, s1w, s2w, out);
}

// Round 7
// 791.819 us; speedup vs baseline: 2.5241x; 1.5878x over previous
//
#include <hip/hip_runtime.h>

#define DD 8
#define SS 64
#define HH 128
#define OUTD 8
#define TT 2049
#define BB 32
#define WINW 16
#define NWIN 128
#define PP 28

typedef __attribute__((ext_vector_type(8))) short short8v;
typedef __attribute__((ext_vector_type(4))) float f32x4;

__device__ __forceinline__ float softplus_f(float x){
    return fmaxf(x, 0.f) + __logf(1.f + __expf(-fabsf(x)));
}
__device__ __forceinline__ float sigmoid_f(float x){
    return 1.f / (1.f + __expf(-x));
}
__device__ __forceinline__ float tanh_f(float x){
    float e = __expf(2.f * x);
    return 1.f - 2.f / (e + 1.f);
}
__device__ __forceinline__ unsigned short f2bf(float f){
    unsigned u = __builtin_bit_cast(unsigned, f);
    unsigned r = (u + 0x7FFFu + ((u >> 16) & 1u)) >> 16;
    return (unsigned short)r;
}
__device__ __forceinline__ unsigned pk2(float a, float b){
    return (unsigned)f2bf(a) | ((unsigned)f2bf(b) << 16);
}

// ---------------- signatures: s1 (B,NWIN,D), s2 (B,NWIN,P) ----------------
__global__ void sig_kernel(const float* __restrict__ x,
                           float* __restrict__ s1o, float* __restrict__ s2o){
    int w = blockIdx.x * blockDim.x + threadIdx.x;
    if (w >= BB * NWIN) return;
    int b = w >> 7, n = w & (NWIN - 1);
    const float* xp = x + ((size_t)b * TT + (size_t)n * WINW) * DD;
    float prev[DD], cum[DD], s1v[DD], M[DD][DD];
    #pragma unroll
    for (int i = 0; i < DD; ++i){
        cum[i] = 0.f; s1v[i] = 0.f;
        #pragma unroll
        for (int j = 0; j < DD; ++j) M[i][j] = 0.f;
    }
    #pragma unroll
    for (int i = 0; i < DD; ++i) prev[i] = xp[i];
    for (int t = 0; t < WINW; ++t){
        float cur[DD], del[DD];
        #pragma unroll
        for (int i = 0; i < DD; ++i) cur[i] = xp[(t + 1) * DD + i];
        #pragma unroll
        for (int i = 0; i < DD; ++i) del[i] = cur[i] - prev[i];
        #pragma unroll
        for (int i = 0; i < DD; ++i){
            #pragma unroll
            for (int j = 0; j < DD; ++j) M[i][j] += cum[i] * del[j];
        }
        #pragma unroll
        for (int i = 0; i < DD; ++i){ cum[i] += del[i]; s1v[i] += del[i]; prev[i] = cur[i]; }
    }
    #pragma unroll
    for (int i = 0; i < DD; ++i) s1o[(size_t)w * DD + i] = s1v[i];
    int p = 0;
    #pragma unroll
    for (int i = 0; i < DD; ++i){
        #pragma unroll
        for (int j = i + 1; j < DD; ++j){ s2o[(size_t)w * PP + p] = 0.5f * (M[i][j] - M[j][i]); ++p; }
    }
}

// image position (shorts): k-row k, col nn of a [K/32][64][8] B-image
#define BPOS(k, nn) ((((k) >> 5) * 64 + (((k) >> 3) & 3) * 16 + (nn)) * 8 + ((k) & 7))

// ---------------- main scan: 2 chains per block, 8 waves, reg-resident weights ----------------
__global__ __launch_bounds__(512, 2) void scan_kernel(
    const float* __restrict__ x,
    const float* __restrict__ Wi0, const float* __restrict__ bi0,
    const float* __restrict__ Wi1, const float* __restrict__ bi1,
    const float* __restrict__ Wi2, const float* __restrict__ bi2,
    const float* __restrict__ Wv0, const float* __restrict__ bv0,
    const float* __restrict__ Wv1, const float* __restrict__ bv1,
    const float* __restrict__ Wv2, const float* __restrict__ bv2,
    const float* __restrict__ Wr,  const float* __restrict__ br,
    const float* __restrict__ s1g, const float* __restrict__ s2g,
    float* __restrict__ out)
{
    const int tid = threadIdx.x;
    const int w   = tid >> 6;   // wave 0..7 (= m-tile / d-block)
    const int l   = tid & 63;
    const int lg  = l >> 4;
    const int ln  = l & 15;
    const int b0  = blockIdx.x * 2;

    __shared__ __align__(16) short BpH[2 * 64 * 8];   // h:  col0=A, col1=B
    __shared__ __align__(16) short Bp0[4 * 64 * 8];   // z0: col0=A, col1=B
    __shared__ __align__(16) short Bp1[4 * 64 * 8];   // z1: cols0-3=A dup, 4-7=B dup
    __shared__ __align__(16) short BpV[2 * 64 * 8];   // V:  col c*8+d
    __shared__ __align__(16) short Bp8[4 * 64 * 8];   // t0: col c*8+d
    __shared__ __align__(16) short Bp9[4 * 64 * 8];   // q:  col c*8+d
    __shared__ __align__(16) float s0p[2 * HH], s1p[2 * HH];
    __shared__ __align__(16) float Vl[2 * 512], Rf[2 * 512];
    __shared__ __align__(16) float hfb[2][2][SS];     // [chain][buf][s]
    __shared__ __align__(16) float Cm[2][DD][9];
    __shared__ __align__(16) float bv0L[HH], bv1L[HH], bv2L[512];
    __shared__ __align__(16) float WrL[OUTD * SS];
    __shared__ float brL[OUTD];
    __shared__ __align__(16) float sAll[2 * NWIN * DD];   // 8 KB
    __shared__ __align__(16) float bAll[2 * NWIN * PP];   // 28 KB
    __shared__ __align__(16) float outL[2 * (NWIN + 1) * OUTD];

    // -------- prologue --------
    for (int i = tid; i < 2 * 64 * 8; i += 512){ BpH[i] = 0; BpV[i] = 0; }
    for (int i = tid; i < 4 * 64 * 8; i += 512){ Bp0[i] = 0; Bp1[i] = 0; Bp8[i] = 0; Bp9[i] = 0; }

    // register-resident A-fragments (wave-invariant rows)
    short8v a0f[2], a1f[4];
    short8v a2f0[4], a2f1[4], a2f2[4], a2f3[4];
    #pragma unroll
    for (int ks = 0; ks < 2; ++ks){
        const float* p = Wv0 + (size_t)(w * 16 + ln) * SS + ks * 32 + lg * 8;
        short8v f;
        #pragma unroll
        for (int j = 0; j < 8; ++j) f[j] = (short)f2bf(p[j]);
        a0f[ks] = f;
    }
    #pragma unroll
    for (int ks = 0; ks < 4; ++ks){
        const float* p = Wv1 + (size_t)(w * 16 + ln) * HH + ks * 32 + lg * 8;
        short8v f;
        #pragma unroll
        for (int j = 0; j < 8; ++j) f[j] = (short)f2bf(p[j]);
        a1f[ks] = f;
    }
    #pragma unroll
    for (int ks = 0; ks < 4; ++ks){
        const float* p0 = Wv2 + (size_t)(64 * w + 0 * 16 + ln) * HH + ks * 32 + lg * 8;
        const float* p1 = Wv2 + (size_t)(64 * w + 1 * 16 + ln) * HH + ks * 32 + lg * 8;
        const float* p2 = Wv2 + (size_t)(64 * w + 2 * 16 + ln) * HH + ks * 32 + lg * 8;
        const float* p3 = Wv2 + (size_t)(64 * w + 3 * 16 + ln) * HH + ks * 32 + lg * 8;
        short8v f0, f1, f2, f3;
        #pragma unroll
        for (int j = 0; j < 8; ++j){
            f0[j] = (short)f2bf(p0[j]); f1[j] = (short)f2bf(p1[j]);
            f2[j] = (short)f2bf(p2[j]); f3[j] = (short)f2bf(p3[j]);
        }
        a2f0[ks] = f0; a2f1[ks] = f1; a2f2[ks] = f2; a2f3[ks] = f3;
    }
    if (tid < HH){ bv0L[tid] = bv0[tid]; bv1L[tid] = bv1[tid]; }
    bv2L[tid] = bv2[tid];
    WrL[tid]  = Wr[tid];
    if (tid < OUTD) brL[tid] = br[tid];
    for (int i = tid; i < 2 * NWIN * DD; i += 512){
        int c = i >> 10;   // NWIN*DD = 1024
        sAll[i] = s1g[(size_t)(b0 + c) * NWIN * DD + (i & 1023)];
    }
    for (int i = tid; i < 2 * NWIN * PP; i += 512){
        int c = i / (NWIN * PP);
        bAll[i] = s2g[(size_t)(b0 + c) * NWIN * PP + (i - c * NWIN * PP)];
    }
    __syncthreads();

    // Cm for step 0 (threads 256-383) || initial MLP L0 (threads 0-255)
    if (tid >= 256 && tid < 384){
        int t2 = tid - 256;
        int c = t2 >> 6, d = (t2 >> 3) & 7, e = t2 & 7;
        const float* bco = &bAll[c * (NWIN * PP)];
        float cv = 0.f;
        if (e < d)      cv =  bco[((e * (15 - e)) >> 1) + d - e - 1];
        else if (e > d) cv = -bco[((d * (15 - d)) >> 1) + e - d - 1];
        Cm[c][d][e] = cv;
    }
    if (tid < 256){
        int c = tid >> 7, r = tid & 127;
        float acc = bi0[r];
        const float* x0 = x + (size_t)(b0 + c) * TT * DD;
        #pragma unroll
        for (int k = 0; k < DD; ++k) acc += Wi0[r * DD + k] * x0[k];
        s0p[c * HH + r] = softplus_f(acc);
    }
    __syncthreads();
    if (tid < 256){
        int c = tid >> 7, r = tid & 127;
        float acc = bi1[r];
        const f32x4* wv = (const f32x4*)(Wi1 + (size_t)r * HH);
        const f32x4* zv = (const f32x4*)&s0p[c * HH];
        #pragma unroll 8
        for (int k = 0; k < 32; ++k){
            f32x4 a = wv[k], z = zv[k];
            acc += a.x * z.x + a.y * z.y + a.z * z.z + a.w * z.w;
        }
        s1p[c * HH + r] = softplus_f(acc);
    }
    __syncthreads();
    if (tid < 128){
        int c = tid >> 6, s = tid & 63;
        float acc = bi2[s];
        const f32x4* wv = (const f32x4*)(Wi2 + (size_t)s * HH);
        const f32x4* zv = (const f32x4*)&s1p[c * HH];
        #pragma unroll 8
        for (int k = 0; k < 32; ++k){
            f32x4 a = wv[k], z = zv[k];
            acc += a.x * z.x + a.y * z.y + a.z * z.z + a.w * z.w;
        }
        hfb[c][0][s] = acc;
        BpH[BPOS(s, c)] = (short)f2bf(acc);
    }
    __syncthreads();

    const f32x4 zero4 = {0.f, 0.f, 0.f, 0.f};
    const int rb = w * 16 + lg * 4;

    // -------- scan --------
    for (int n = 0; n < NWIN; ++n){
        // ---- S1: z0 = sp(W0 @ h), cols 0,1 = chains ----
        {
            f32x4 acc = zero4;
            acc = __builtin_amdgcn_mfma_f32_16x16x32_bf16(a0f[0], *(const short8v*)&BpH[(0 * 64 + l) * 8], acc, 0, 0, 0);
            acc = __builtin_amdgcn_mfma_f32_16x16x32_bf16(a0f[1], *(const short8v*)&BpH[(1 * 64 + l) * 8], acc, 0, 0, 0);
            if (ln < 2){
                int c = ln;
                f32x4 bv = *(const f32x4*)&bv0L[rb];
                f32x4 sg; float z[4];
                #pragma unroll
                for (int r = 0; r < 4; ++r){
                    float p = acc[r] + bv[r];
                    z[r] = softplus_f(p); sg[r] = sigmoid_f(p);
                }
                *(f32x4*)&s0p[c * HH + rb] = sg;
                uint2 pk; pk.x = pk2(z[0], z[1]); pk.y = pk2(z[2], z[3]);
                *(uint2*)&Bp0[BPOS(rb, c)] = pk;
            }
        }
        __syncthreads();

        // ---- S3: z1 = sp(W1 @ z0); chain c -> Bp1 cols 4c..4c+3 (dup x4) ----
        {
            f32x4 acc = zero4;
            #pragma unroll
            for (int ks = 0; ks < 4; ++ks)
                acc = __builtin_amdgcn_mfma_f32_16x16x32_bf16(a1f[ks], *(const short8v*)&Bp0[(ks * 64 + l) * 8], acc, 0, 0, 0);
            if (ln < 2){
                int c = ln;
                f32x4 bv = *(const f32x4*)&bv1L[rb];
                f32x4 sg; float z[4];
                #pragma unroll
                for (int r = 0; r < 4; ++r){
                    float p = acc[r] + bv[r];
                    z[r] = softplus_f(p); sg[r] = sigmoid_f(p);
                }
                *(f32x4*)&s1p[c * HH + rb] = sg;
                uint2 pk; pk.x = pk2(z[0], z[1]); pk.y = pk2(z[2], z[3]);
                #pragma unroll
                for (int cc = 0; cc < 4; ++cc) *(uint2*)&Bp1[BPOS(rb, c * 4 + cc)] = pk;
            }
        }
        __syncthreads();

        // ---- S4: V_d = tanh(W2_d @ z1 + bv2), d = w; lanes 0-7: c=ln>>2, t=ln&3 ----
        {
            short8v bf[4];
            #pragma unroll
            for (int ks = 0; ks < 4; ++ks) bf[ks] = *(const short8v*)&Bp1[(ks * 64 + l) * 8];
            f32x4 acc0 = zero4, acc1 = zero4, acc2 = zero4, acc3 = zero4;
            #pragma unroll
            for (int ks = 0; ks < 4; ++ks){
                acc0 = __builtin_amdgcn_mfma_f32_16x16x32_bf16(a2f0[ks], bf[ks], acc0, 0, 0, 0);
                acc1 = __builtin_amdgcn_mfma_f32_16x16x32_bf16(a2f1[ks], bf[ks], acc1, 0, 0, 0);
                acc2 = __builtin_amdgcn_mfma_f32_16x16x32_bf16(a2f2[ks], bf[ks], acc2, 0, 0, 0);
                acc3 = __builtin_amdgcn_mfma_f32_16x16x32_bf16(a2f3[ks], bf[ks], acc3, 0, 0, 0);
            }
            if (ln < 8){
                int c = ln >> 2, t = ln & 3;
                f32x4 av = (t == 0) ? acc0 : (t == 1) ? acc1 : (t == 2) ? acc2 : acc3;
                int r4 = 64 * w + t * 16 + lg * 4;
                f32x4 bv = *(const f32x4*)&bv2L[r4];
                f32x4 vv;
                #pragma unroll
                for (int r = 0; r < 4; ++r) vv[r] = tanh_f(av[r] + bv[r]);
                *(f32x4*)&Vl[c * 512 + r4] = vv;
                int sl = t * 16 + lg * 4;
                uint2 pk; pk.x = pk2(vv[0], vv[1]); pk.y = pk2(vv[2], vv[3]);
                *(uint2*)&BpV[BPOS(sl, c * 8 + w)] = pk;
            }
        }
        __syncthreads();

        // ---- S7: Y = W0 @ V^T (N=16: c*8+e); t0[:,c,d] = s0p * sum_e Cm[c][d][e] Y[:,c,e] ----
        {
            f32x4 acc = zero4;
            acc = __builtin_amdgcn_mfma_f32_16x16x32_bf16(a0f[0], *(const short8v*)&BpV[(0 * 64 + l) * 8], acc, 0, 0, 0);
            acc = __builtin_amdgcn_mfma_f32_16x16x32_bf16(a0f[1], *(const short8v*)&BpV[(1 * 64 + l) * 8], acc, 0, 0, 0);
            const int c = ln >> 3, d = ln & 7;
            float tm0 = 0.f, tm1 = 0.f, tm2 = 0.f, tm3 = 0.f;
            #pragma unroll
            for (int e = 0; e < 8; ++e){
                float ce = Cm[c][d][e];
                int src = (l & 48) | (ln & 8) | e;
                tm0 += ce * __shfl(acc[0], src);
                tm1 += ce * __shfl(acc[1], src);
                tm2 += ce * __shfl(acc[2], src);
                tm3 += ce * __shfl(acc[3], src);
            }
            f32x4 sg = *(const f32x4*)&s0p[c * HH + rb];
            uint2 pk; pk.x = pk2(sg[0] * tm0, sg[1] * tm1); pk.y = pk2(sg[2] * tm2, sg[3] * tm3);
            *(uint2*)&Bp8[BPOS(rb, ln)] = pk;
        }
        __syncthreads();

        // ---- S8: q = s1' * (W1 @ t0) (N=16) ----
        {
            f32x4 acc = zero4;
            #pragma unroll
            for (int ks = 0; ks < 4; ++ks)
                acc = __builtin_amdgcn_mfma_f32_16x16x32_bf16(a1f[ks], *(const short8v*)&Bp8[(ks * 64 + l) * 8], acc, 0, 0, 0);
            int c = ln >> 3;
            f32x4 sg = *(const f32x4*)&s1p[c * HH + rb];
            uint2 pk; pk.x = pk2(sg[0] * acc[0], sg[1] * acc[1]); pk.y = pk2(sg[2] * acc[2], sg[3] * acc[3]);
            *(uint2*)&Bp9[BPOS(rb, ln)] = pk;
        }
        __syncthreads();

        // ---- S9: R_d = (1-V_d^2) * (W2_d @ q[:,c,d]), d = w; lanes (ln&7)==w, c=ln>>3 ----
        {
            short8v bf[4];
            #pragma unroll
            for (int ks = 0; ks < 4; ++ks) bf[ks] = *(const short8v*)&Bp9[(ks * 64 + l) * 8];
            f32x4 acc0 = zero4, acc1 = zero4, acc2 = zero4, acc3 = zero4;
            #pragma unroll
            for (int ks = 0; ks < 4; ++ks){
                acc0 = __builtin_amdgcn_mfma_f32_16x16x32_bf16(a2f0[ks], bf[ks], acc0, 0, 0, 0);
                acc1 = __builtin_amdgcn_mfma_f32_16x16x32_bf16(a2f1[ks], bf[ks], acc1, 0, 0, 0);
                acc2 = __builtin_amdgcn_mfma_f32_16x16x32_bf16(a2f2[ks], bf[ks], acc2, 0, 0, 0);
                acc3 = __builtin_amdgcn_mfma_f32_16x16x32_bf16(a2f3[ks], bf[ks], acc3, 0, 0, 0);
            }
            if ((ln & 7) == w){
                int c = ln >> 3;
                #pragma unroll
                for (int t = 0; t < 4; ++t){
                    f32x4 av = (t == 0) ? acc0 : (t == 1) ? acc1 : (t == 2) ? acc2 : acc3;
                    int r4 = 64 * w + t * 16 + lg * 4;
                    f32x4 vv = *(const f32x4*)&Vl[c * 512 + r4];
                    f32x4 rr;
                    #pragma unroll
                    for (int r = 0; r < 4; ++r) rr[r] = (1.f - vv[r] * vv[r]) * av[r];
                    *(f32x4*)&Rf[c * 512 + r4] = rr;
                }
            }
        }
        __syncthreads();

        // ---- upd: waves 0-1 h-update | 2-3 readout | 4-5 Cm(n+1), per chain ----
        {
            const int cur = n & 1;
            if (w < 2){
                int c = w, s = l;
                float hN = hfb[c][cur][s];
                #pragma unroll
                for (int d = 0; d < DD; ++d)
                    hN += sAll[c * (NWIN * DD) + n * DD + d] * Vl[c * 512 + d * 64 + s]
                        + Rf[c * 512 + d * 64 + s];
                hfb[c][cur ^ 1][s] = hN;
                BpH[BPOS(s, c)] = (short)f2bf(hN);
            } else if (w < 4){
                int c = w - 2;
                int o = l >> 3, qq = l & 7;
                f32x4 w0 = *(const f32x4*)&WrL[o * SS + qq * 8];
                f32x4 w1 = *(const f32x4*)&WrL[o * SS + qq * 8 + 4];
                f32x4 h0 = *(const f32x4*)&hfb[c][cur][qq * 8];
                f32x4 h1 = *(const f32x4*)&hfb[c][cur][qq * 8 + 4];
                float acc = w0.x*h0.x + w0.y*h0.y + w0.z*h0.z + w0.w*h0.w
                          + w1.x*h1.x + w1.y*h1.y + w1.z*h1.z + w1.w*h1.w;
                acc += __shfl_xor(acc, 1); acc += __shfl_xor(acc, 2); acc += __shfl_xor(acc, 4);
                if (qq == 0) outL[c * (NWIN + 1) * OUTD + n * OUTD + o] = brL[o] + acc;
            } else if (w < 6){
                int c = w - 4;
                if (n + 1 < NWIN){
                    int d = l >> 3, e = l & 7;
                    const float* bco = &bAll[c * (NWIN * PP) + (n + 1) * PP];
                    float cv = 0.f;
                    if (e < d)      cv =  bco[((e * (15 - e)) >> 1) + d - e - 1];
                    else if (e > d) cv = -bco[((d * (15 - d)) >> 1) + e - d - 1];
                    Cm[c][d][e] = cv;
                }
            }
        }
        __syncthreads();
    }

    // final readout: h_NWIN in hfb[c][0] (NWIN even)
    if (w == 2 || w == 3){
        int c = w - 2;
        int o = l >> 3, qq = l & 7;
        f32x4 w0 = *(const f32x4*)&WrL[o * SS + qq * 8];
        f32x4 w1 = *(const f32x4*)&WrL[o * SS + qq * 8 + 4];
        f32x4 h0 = *(const f32x4*)&hfb[c][0][qq * 8];
        f32x4 h1 = *(const f32x4*)&hfb[c][0][qq * 8 + 4];
        float acc = w0.x*h0.x + w0.y*h0.y + w0.z*h0.z + w0.w*h0.w
                  + w1.x*h1.x + w1.y*h1.y + w1.z*h1.z + w1.w*h1.w;
        acc += __shfl_xor(acc, 1); acc += __shfl_xor(acc, 2); acc += __shfl_xor(acc, 4);
        if (qq == 0) outL[c * (NWIN + 1) * OUTD + NWIN * OUTD + o] = brL[o] + acc;
    }
    __syncthreads();

    for (int i = tid; i < 2 * (NWIN + 1) * OUTD; i += 512){
        int c = (i >= (NWIN + 1) * OUTD) ? 1 : 0;
        int rem = i - c * (NWIN + 1) * OUTD;
        out[(size_t)(b0 + c) * (NWIN + 1) * OUTD + rem] = outL[i];
    }
}

extern "C" void kernel_launch(void* const* d_in, const int* in_sizes, int n_in,
                              void* d_out, int out_size, void* d_ws, size_t ws_size,
                              hipStream_t stream){
    const float* x   = (const float*)d_in[1];
    const float* Wi0 = (const float*)d_in[2];
    const float* bi0 = (const float*)d_in[3];
    const float* Wi1 = (const float*)d_in[4];
    const float* bi1 = (const float*)d_in[5];
    const float* Wi2 = (const float*)d_in[6];
    const float* bi2 = (const float*)d_in[7];
    const float* Wv0 = (const float*)d_in[8];
    const float* bv0 = (const float*)d_in[9];
    const float* Wv1 = (const float*)d_in[10];
    const float* bv1 = (const float*)d_in[11];
    const float* Wv2 = (const float*)d_in[12];
    const float* bv2 = (const float*)d_in[13];
    const float* Wr  = (const float*)d_in[14];
    const float* br  = (const float*)d_in[15];
    float* out = (float*)d_out;

    float* s1w = (float*)d_ws;
    float* s2w = s1w + (size_t)BB * NWIN * DD;

    sig_kernel<<<(BB * NWIN + 255) / 256, 256, 0, stream>>>(x, s1w, s2w);
    scan_kernel<<<BB / 2, 512, 0, stream>>>(x, Wi0, bi0, Wi1, bi1, Wi2, bi2,
                                            Wv0, bv0, Wv1, bv1, Wv2, bv2,
                                            Wr, br, s1w, s2w, out);
}